// Round 1
// 203.476 us; speedup vs baseline: 1.0810x; 1.0810x over previous
//
#include <hip/hip_runtime.h>
#include <hip/hip_bf16.h>

typedef unsigned short u16;
typedef unsigned int u32;
typedef short bf16x8 __attribute__((ext_vector_type(8)));
typedef float f32x4 __attribute__((ext_vector_type(4)));
typedef u16 u16x8 __attribute__((ext_vector_type(8)));

#define HID 1024
#define BATCH 4096
#define KTOT 2048       // concat K: [x | h_prev]
#define NT 32           // K tiles of 64
#define LDS_OP 16384    // elems per [buf][op] region: 256 rows x 64 k

__device__ __forceinline__ u16 f2bf(float f) {
  u32 v = __builtin_bit_cast(u32, f);
  u32 r = (v + 0x7fffu + ((v >> 16) & 1u)) >> 16;  // round-nearest-even
  return (u16)r;
}
__device__ __forceinline__ float sigmoid_fast(float x) {
  return 1.0f / (1.0f + __expf(-x));
}
__device__ __forceinline__ float tanh_fast(float x) {
  return 2.0f * sigmoid_fast(2.0f * x) - 1.0f;
}
__device__ __forceinline__ void gl_lds16(const void* g, void* l) {
  __builtin_amdgcn_global_load_lds(
      (const __attribute__((address_space(1))) u32*)g,
      (__attribute__((address_space(3))) u32*)l, 16, 0, 0);
}

// ---------------------------------------------------------------------------
// prep_all: fused prep. Blocks [0,4096) build xh (bf16 [B][2048]); blocks
// [4096,6144) build Bt[n'][k] (bf16, gate-interleaved n') via LDS transpose.
// Fusing lets the two independent passes overlap and saves a graph edge.
// ---------------------------------------------------------------------------
__global__ __launch_bounds__(256) void prep_all(
    const float* __restrict__ x, const float* __restrict__ hp,
    const float* __restrict__ igx, const float* __restrict__ fgx,
    const float* __restrict__ ogx, const float* __restrict__ cgx,
    const float* __restrict__ igu, const float* __restrict__ fgu,
    const float* __restrict__ ogu, const float* __restrict__ cgu,
    u16* __restrict__ xh, u16* __restrict__ bt) {
  __shared__ u16 lds[64 * 66];
  if (blockIdx.x < 4096) {
    // ---- xh builder ----
    int c = blockIdx.x * 256 + threadIdx.x;  // chunk id, 8 elems each
    int row = c >> 8;
    int col0 = (c & 255) << 3;
    const float* src = (col0 < 1024)
                           ? (x + (size_t)row * 1024 + col0)
                           : (hp + (size_t)row * 1024 + (col0 - 1024));
    f32x4 a = *(const f32x4*)(src);
    f32x4 b = *(const f32x4*)(src + 4);
    u16x8 v;
#pragma unroll
    for (int j = 0; j < 4; ++j) { v[j] = f2bf(a[j]); v[j + 4] = f2bf(b[j]); }
    *(u16x8*)(xh + (size_t)row * KTOT + col0) = v;
    return;
  }
  // ---- weight transpose: n' = (h/16)*64 + g*16 + (h%16), k = which*1024+ksrc
  const float* srcs[8] = {igx, fgx, ogx, cgx, igu, fgu, ogu, cgu};
  int bid = blockIdx.x - 4096;
  int m = bid >> 8;            // matrix 0..7
  int tile = bid & 255;        // 64x64 tile
  int th = tile & 15, tk = tile >> 4;
  int h0 = th << 6, k0 = tk << 6;
  int g = m & 3, which = m >> 2;
  const float* W = srcs[m] + (size_t)k0 * HID + h0;

  int t = threadIdx.x;
  int r1 = t >> 4;
  int c1 = (t & 15) << 2;
#pragma unroll
  for (int p = 0; p < 4; ++p) {
    int row = (p << 4) + r1;
    f32x4 v = *(const f32x4*)(W + (size_t)row * HID + c1);
    u32 p0 = (u32)f2bf(v[0]) | ((u32)f2bf(v[1]) << 16);
    u32 p1 = (u32)f2bf(v[2]) | ((u32)f2bf(v[3]) << 16);
    u32* d = (u32*)&lds[row * 66 + c1];
    d[0] = p0;
    d[1] = p1;
  }
  __syncthreads();
  int nl = t >> 2;
  int kc = t & 3;
  int row_np = ((h0 >> 4) << 6) + ((nl >> 4) << 6) + (g << 4) + (nl & 15);
  size_t dst = (size_t)row_np * KTOT + (size_t)which * 1024 + k0;
  u16x8 a2, b2;
#pragma unroll
  for (int j = 0; j < 8; ++j) {
    a2[j] = lds[(kc * 8 + j) * 66 + nl];
    b2[j] = lds[(kc * 8 + 32 + j) * 66 + nl];
  }
  *(u16x8*)(&bt[dst + kc * 8]) = a2;
  *(u16x8*)(&bt[dst + kc * 8 + 32]) = b2;
}

// ---------------------------------------------------------------------------
// Staging: half-tile stream. s&3: 0=B rows0-127, 1=B rows128-255,
// 2=A rows0-127, 3=A rows128-255; ts=s>>2 selects K-tile, buf=ts&1.
// Each thread: 2x global_load_lds(16B). LDS dest linear (required); the
// k-chunk swizzle (chunk ^= row&7) is applied on the GLOBAL source address
// (both-sides rule), and undone on ds_read. B-halves stream first so the
// only same-buffer stage (phase 3: s=4t+8 -> B0 of t+2 into buf t&1) writes
// the B region while phase 3 only ds_reads the A region.
// ---------------------------------------------------------------------------
__device__ __forceinline__ void stage(int s, const u16* aS, const u16* bS,
                                      u16* lds, int sx) {
  if (s >= 4 * NT) return;
  int ts = s >> 2, hh = s & 3;
  int op = (hh >> 1) ^ 1;              // 0,1 -> B (op=1); 2,3 -> A (op=0)
  int rb = (hh & 1) << 7;              // row base within 256-row tile
  const u16* src = (op ? bS : aS) + (size_t)rb * KTOT + ts * 64;
  u16* dst = lds + ((((ts & 1) << 1) + op) * LDS_OP) + (rb << 6) + sx * 8;
  gl_lds16(src, dst);                                   // rows rb+0..63
  gl_lds16(src + (size_t)64 * KTOT, dst + 4096);        // rows rb+64..127
}

// ---------------------------------------------------------------------------
// lstm_gemm: 256x256 tile, 8 waves (2Mx4N), BK=64, 8-phase schedule with
// counted vmcnt (T3+T4), setprio around MFMA clusters (T5), XOR k-chunk
// swizzle (conflict-free ds_read_b128, T2-equivalent). 128 KiB LDS dbuf.
// Grid 16x16 = 256 blocks = 1 block/CU. Fused LSTM epilogue.
// ---------------------------------------------------------------------------
__global__ __launch_bounds__(512, 2) void lstm_gemm(
    const u16* __restrict__ xh, const u16* __restrict__ bt,
    const float* __restrict__ cprev,
    const float* __restrict__ ib, const float* __restrict__ fb,
    const float* __restrict__ ob, const float* __restrict__ cb,
    float* __restrict__ hout, float* __restrict__ cout) {
  __shared__ __align__(16) u16 lds[2 * 2 * LDS_OP];   // 128 KiB

  int sx = threadIdx.x;
  int brow = blockIdx.x, bcol = blockIdx.y;
  int w = sx >> 6, l = sx & 63;
  int wr = (w >> 2) << 7;              // 0 | 128 (WARPS_M = 2)
  int wc = (w & 3) << 6;               // 0,64,128,192 (WARPS_N = 4)
  int lrow = l & 15, q = l >> 4;
  int grow = brow << 8;

  // staging source pointers (per-thread global addr carries the swizzle)
  int prow = sx >> 3;                                    // 0..63
  int koff = ((sx & 7) ^ (prow & 7)) << 3;               // swizzled k elems
  const u16* aSrc = xh + (size_t)(grow + prow) * KTOT + koff;
  const u16* bSrc = bt + (size_t)(bcol * 256 + prow) * KTOT + koff;

  // fragment read offsets: physical chunk = logical ^ (row&7); row&7==lrow&7
  int aoff = (wr + lrow) << 6;
  int boff = (wc + lrow) << 6;
  int pc0 = (q ^ (lrow & 7)) << 3;          // k-step 0, quad q
  int pc1 = ((q + 4) ^ (lrow & 7)) << 3;    // k-step 1

  f32x4 acc[8][4] = {};
  bf16x8 af[2][2], bfr[4][2];

  // prologue: tile0 {B0,B1,A0,A1} + tile1 B0; wait tile0 (8 oldest loads)
  stage(0, aSrc, bSrc, lds, sx);
  stage(1, aSrc, bSrc, lds, sx);
  stage(2, aSrc, bSrc, lds, sx);
  stage(3, aSrc, bSrc, lds, sx);
  stage(4, aSrc, bSrc, lds, sx);
  asm volatile("s_waitcnt vmcnt(2)");
  __builtin_amdgcn_s_barrier();
  __builtin_amdgcn_sched_barrier(0);

#define RDA(i, s) (*(const bf16x8*)(Ab + aoff + (i) * 1024 + ((s) ? pc1 : pc0)))
#define RDB(j, s) (*(const bf16x8*)(Bb + boff + (j) * 1024 + ((s) ? pc1 : pc0)))

// one phase: ds-read subtile || issue 1 half-tile stage -> bar -> lgkm(0)
// -> setprio(1) -> 16 MFMA -> setprio(0). Caller adds boundary+barrier.
#define DO_PHASE(K_, SS_)                                                     \
  {                                                                           \
    af[0][0] = RDA(2 * (K_), 0);                                              \
    af[0][1] = RDA(2 * (K_), 1);                                              \
    af[1][0] = RDA(2 * (K_) + 1, 0);                                          \
    af[1][1] = RDA(2 * (K_) + 1, 1);                                          \
    if ((K_) == 0) {                                                          \
      bfr[0][0] = RDB(0, 0); bfr[0][1] = RDB(0, 1);                           \
      bfr[1][0] = RDB(1, 0); bfr[1][1] = RDB(1, 1);                           \
      bfr[2][0] = RDB(2, 0); bfr[2][1] = RDB(2, 1);                           \
      bfr[3][0] = RDB(3, 0); bfr[3][1] = RDB(3, 1);                           \
    }                                                                         \
    stage(SS_, aSrc, bSrc, lds, sx);                                          \
    __builtin_amdgcn_s_barrier();                                             \
    asm volatile("s_waitcnt lgkmcnt(0)");                                     \
    __builtin_amdgcn_sched_barrier(0);                                        \
    __builtin_amdgcn_s_setprio(1);                                            \
    _Pragma("unroll") for (int s2 = 0; s2 < 2; ++s2) {                        \
      _Pragma("unroll") for (int j = 0; j < 4; ++j) {                         \
        acc[2 * (K_)][j] = __builtin_amdgcn_mfma_f32_16x16x32_bf16(           \
            af[0][s2], bfr[j][s2], acc[2 * (K_)][j], 0, 0, 0);                \
        acc[2 * (K_) + 1][j] = __builtin_amdgcn_mfma_f32_16x16x32_bf16(       \
            af[1][s2], bfr[j][s2], acc[2 * (K_) + 1][j], 0, 0, 0);            \
      }                                                                       \
    }                                                                         \
    __builtin_amdgcn_s_setprio(0);                                            \
    __builtin_amdgcn_sched_barrier(0);                                        \
  }

#pragma unroll 2
  for (int t = 0; t < NT; ++t) {
    const u16* Ab = lds + ((t & 1) << 1) * LDS_OP;
    const u16* Bb = Ab + LDS_OP;
    int s0 = 4 * t + 5;                 // stage stream runs 5 half-tiles ahead
    DO_PHASE(0, s0)                     // i=0,1 ; all B frags
    __builtin_amdgcn_s_barrier();
    DO_PHASE(1, s0 + 1)                 // i=2,3
    __builtin_amdgcn_s_barrier();
    DO_PHASE(2, s0 + 2)                 // i=4,5
    __builtin_amdgcn_s_barrier();
    DO_PHASE(3, s0 + 3)                 // i=6,7 ; stages B0(t+2) into cur buf
    // boundary: next tile fully landed; only slot(t,3)'s 2 loads may fly
    if (t < NT - 2) asm volatile("s_waitcnt vmcnt(2)");
    else            asm volatile("s_waitcnt vmcnt(0)");
    __builtin_amdgcn_s_barrier();
  }
#undef DO_PHASE
#undef RDA
#undef RDB

  // Epilogue: n-frag j = gate (i,f,o,c) for hidden cols of sub-block sb.
  int sb = (bcol << 2) + (w & 3);
  int hcol = (sb << 4) + lrow;
  float bi = ib[hcol];
  float bff = fb[hcol];
  float bo = ob[hcol];
  float bc = cb[hcol];

#pragma unroll
  for (int i = 0; i < 8; ++i) {
    int row0 = grow + wr + i * 16 + q * 4;
#pragma unroll
    for (int r = 0; r < 4; ++r) {
      size_t idx = (size_t)(row0 + r) * HID + hcol;
      float gi = sigmoid_fast(acc[i][0][r] + bi);
      float gf = sigmoid_fast(acc[i][1][r] + bff);
      float go = sigmoid_fast(acc[i][2][r] + bo);
      float gc = tanh_fast(acc[i][3][r] + bc);
      float cp = cprev[idx];
      float cv = gf * cp + gi * gc;
      hout[idx] = go * tanh_fast(cv);
      cout[idx] = cv;
    }
  }
}

extern "C" void kernel_launch(void* const* d_in, const int* in_sizes, int n_in,
                              void* d_out, int out_size, void* d_ws, size_t ws_size,
                              hipStream_t stream) {
  const float* x   = (const float*)d_in[0];
  const float* hp  = (const float*)d_in[1];
  const float* cp  = (const float*)d_in[2];
  const float* igx = (const float*)d_in[3];
  const float* igu = (const float*)d_in[4];
  const float* ib  = (const float*)d_in[5];
  const float* fgx = (const float*)d_in[6];
  const float* fgu = (const float*)d_in[7];
  const float* fb  = (const float*)d_in[8];
  const float* ogx = (const float*)d_in[9];
  const float* ogu = (const float*)d_in[10];
  const float* ob  = (const float*)d_in[11];
  const float* cgx = (const float*)d_in[12];
  const float* cgu = (const float*)d_in[13];
  const float* cb  = (const float*)d_in[14];

  u16* bt = (u16*)d_ws;                         // [4096][2048] bf16 = 16 MiB
  u16* xh = bt + (size_t)4096 * 2048;           // [4096][2048] bf16 = 16 MiB
  float* hout = (float*)d_out;
  float* cout = hout + (size_t)BATCH * HID;

  prep_all<<<6144, 256, 0, stream>>>(x, hp, igx, fgx, ogx, cgx,
                                     igu, fgu, ogu, cgu, xh, bt);
  lstm_gemm<<<dim3(16, 16), 512, 0, stream>>>(xh, bt, cp, ib, fb, ob, cb,
                                              hout, cout);
}

// Round 2
// 202.832 us; speedup vs baseline: 1.0844x; 1.0032x over previous
//
#include <hip/hip_runtime.h>
#include <hip/hip_bf16.h>

typedef unsigned short u16;
typedef unsigned int u32;
typedef short bf16x8 __attribute__((ext_vector_type(8)));
typedef float f32x4 __attribute__((ext_vector_type(4)));
typedef u16 u16x8 __attribute__((ext_vector_type(8)));

#define HID 1024
#define BATCH 4096
#define KTOT 2048       // concat K: [x | h_prev]
#define NT 32           // K tiles of 64
#define LDS_OP 16384    // elems per [buf][op] region: 256 rows x 64 k

__device__ __forceinline__ u16 f2bf(float f) {
  u32 v = __builtin_bit_cast(u32, f);
  u32 r = (v + 0x7fffu + ((v >> 16) & 1u)) >> 16;  // round-nearest-even
  return (u16)r;
}
__device__ __forceinline__ float sigmoid_fast(float x) {
  return 1.0f / (1.0f + __expf(-x));
}
__device__ __forceinline__ float tanh_fast(float x) {
  return 2.0f * sigmoid_fast(2.0f * x) - 1.0f;
}
__device__ __forceinline__ void gl_lds16(const void* g, void* l) {
  __builtin_amdgcn_global_load_lds(
      (const __attribute__((address_space(1))) u32*)g,
      (__attribute__((address_space(3))) u32*)l, 16, 0, 0);
}

// ---------------------------------------------------------------------------
// prep_all: fused prep. Blocks [0,4096) build xh (bf16 [B][2048]); blocks
// [4096,6144) build Bt[n'][k] (bf16, gate-interleaved n') via LDS transpose.
// ---------------------------------------------------------------------------
__global__ __launch_bounds__(256) void prep_all(
    const float* __restrict__ x, const float* __restrict__ hp,
    const float* __restrict__ igx, const float* __restrict__ fgx,
    const float* __restrict__ ogx, const float* __restrict__ cgx,
    const float* __restrict__ igu, const float* __restrict__ fgu,
    const float* __restrict__ ogu, const float* __restrict__ cgu,
    u16* __restrict__ xh, u16* __restrict__ bt) {
  __shared__ u16 lds[64 * 66];
  if (blockIdx.x < 4096) {
    // ---- xh builder ----
    int c = blockIdx.x * 256 + threadIdx.x;  // chunk id, 8 elems each
    int row = c >> 8;
    int col0 = (c & 255) << 3;
    const float* src = (col0 < 1024)
                           ? (x + (size_t)row * 1024 + col0)
                           : (hp + (size_t)row * 1024 + (col0 - 1024));
    f32x4 a = *(const f32x4*)(src);
    f32x4 b = *(const f32x4*)(src + 4);
    u16x8 v;
#pragma unroll
    for (int j = 0; j < 4; ++j) { v[j] = f2bf(a[j]); v[j + 4] = f2bf(b[j]); }
    *(u16x8*)(xh + (size_t)row * KTOT + col0) = v;
    return;
  }
  // ---- weight transpose: n' = (h/16)*64 + g*16 + (h%16), k = which*1024+ksrc
  const float* srcs[8] = {igx, fgx, ogx, cgx, igu, fgu, ogu, cgu};
  int bid = blockIdx.x - 4096;
  int m = bid >> 8;            // matrix 0..7
  int tile = bid & 255;        // 64x64 tile
  int th = tile & 15, tk = tile >> 4;
  int h0 = th << 6, k0 = tk << 6;
  int g = m & 3, which = m >> 2;
  const float* W = srcs[m] + (size_t)k0 * HID + h0;

  int t = threadIdx.x;
  int r1 = t >> 4;
  int c1 = (t & 15) << 2;
#pragma unroll
  for (int p = 0; p < 4; ++p) {
    int row = (p << 4) + r1;
    f32x4 v = *(const f32x4*)(W + (size_t)row * HID + c1);
    u32 p0 = (u32)f2bf(v[0]) | ((u32)f2bf(v[1]) << 16);
    u32 p1 = (u32)f2bf(v[2]) | ((u32)f2bf(v[3]) << 16);
    u32* d = (u32*)&lds[row * 66 + c1];
    d[0] = p0;
    d[1] = p1;
  }
  __syncthreads();
  int nl = t >> 2;
  int kc = t & 3;
  int row_np = ((h0 >> 4) << 6) + ((nl >> 4) << 6) + (g << 4) + (nl & 15);
  size_t dst = (size_t)row_np * KTOT + (size_t)which * 1024 + k0;
  u16x8 a2, b2;
#pragma unroll
  for (int j = 0; j < 8; ++j) {
    a2[j] = lds[(kc * 8 + j) * 66 + nl];
    b2[j] = lds[(kc * 8 + 32 + j) * 66 + nl];
  }
  *(u16x8*)(&bt[dst + kc * 8]) = a2;
  *(u16x8*)(&bt[dst + kc * 8 + 32]) = b2;
}

// ---------------------------------------------------------------------------
// Staging: half-tile stream. s&3: 0=B rows0-127, 1=B rows128-255,
// 2=A rows0-127, 3=A rows128-255; ts=s>>2 selects K-tile, buf=ts&1.
// Each thread: 2x global_load_lds(16B). LDS dest linear (required); the
// k-chunk swizzle (chunk ^= row&7) is applied on the GLOBAL source address
// (both-sides rule), and undone on ds_read.
//
// Stream offset s0=4t+6 (max race-free depth with 2 buffers):
//   phase 0,1 of tile t stage A0,A1(t+1) -> buf (t+1)&1 A region (dead since
//     the boundary barrier);
//   phase 2,3 of tile t stage B0,B1(t+2) -> buf t&1 B region (dead after
//     phase 0's trailing barrier — all 8 B-frags are read in phase 0).
// Boundary wait vmcnt(4): exactly the B0/B1(t+2) loads stay in flight; the
// A halves of tile t+1 get ~3 phases of flight time instead of <1.
// ---------------------------------------------------------------------------
__device__ __forceinline__ void stage(int s, const u16* aS, const u16* bS,
                                      u16* lds, int sx) {
  if (s >= 4 * NT) return;
  int ts = s >> 2, hh = s & 3;
  int op = (hh >> 1) ^ 1;              // 0,1 -> B (op=1); 2,3 -> A (op=0)
  int rb = (hh & 1) << 7;              // row base within 256-row tile
  const u16* src = (op ? bS : aS) + (size_t)rb * KTOT + ts * 64;
  u16* dst = lds + ((((ts & 1) << 1) + op) * LDS_OP) + (rb << 6) + sx * 8;
  gl_lds16(src, dst);                                   // rows rb+0..63
  gl_lds16(src + (size_t)64 * KTOT, dst + 4096);        // rows rb+64..127
}

// ---------------------------------------------------------------------------
// lstm_gemm: 256x256 tile, 8 waves (2Mx4N), BK=64, 8-phase schedule with
// counted vmcnt (T3+T4), setprio around MFMA clusters (T5), XOR k-chunk
// swizzle (conflict-free ds_read_b128, T2-equivalent). 128 KiB LDS dbuf.
// Grid 16x16 = 256 blocks = 1 block/CU. Fused LSTM epilogue.
// ---------------------------------------------------------------------------
__global__ __launch_bounds__(512, 2) void lstm_gemm(
    const u16* __restrict__ xh, const u16* __restrict__ bt,
    const float* __restrict__ cprev,
    const float* __restrict__ ib, const float* __restrict__ fb,
    const float* __restrict__ ob, const float* __restrict__ cb,
    float* __restrict__ hout, float* __restrict__ cout) {
  __shared__ __align__(16) u16 lds[2 * 2 * LDS_OP];   // 128 KiB

  int sx = threadIdx.x;
  int brow = blockIdx.x, bcol = blockIdx.y;
  int w = sx >> 6, l = sx & 63;
  int wr = (w >> 2) << 7;              // 0 | 128 (WARPS_M = 2)
  int wc = (w & 3) << 6;               // 0,64,128,192 (WARPS_N = 4)
  int lrow = l & 15, q = l >> 4;
  int grow = brow << 8;

  // staging source pointers (per-thread global addr carries the swizzle)
  int prow = sx >> 3;                                    // 0..63
  int koff = ((sx & 7) ^ (prow & 7)) << 3;               // swizzled k elems
  const u16* aSrc = xh + (size_t)(grow + prow) * KTOT + koff;
  const u16* bSrc = bt + (size_t)(bcol * 256 + prow) * KTOT + koff;

  // fragment read offsets: physical chunk = logical ^ (row&7); row&7==lrow&7
  int aoff = (wr + lrow) << 6;
  int boff = (wc + lrow) << 6;
  int pc0 = (q ^ (lrow & 7)) << 3;          // k-step 0, quad q
  int pc1 = ((q + 4) ^ (lrow & 7)) << 3;    // k-step 1

  f32x4 acc[8][4] = {};
  bf16x8 af[2][2], bfr[4][2];

  // prologue: tile0 {B0,B1,A0,A1} + tile1 {B0,B1}; wait tile0 (8 oldest)
  stage(0, aSrc, bSrc, lds, sx);
  stage(1, aSrc, bSrc, lds, sx);
  stage(2, aSrc, bSrc, lds, sx);
  stage(3, aSrc, bSrc, lds, sx);
  stage(4, aSrc, bSrc, lds, sx);
  stage(5, aSrc, bSrc, lds, sx);
  asm volatile("s_waitcnt vmcnt(4)");
  __builtin_amdgcn_s_barrier();
  __builtin_amdgcn_sched_barrier(0);

#define RDA(i, s) (*(const bf16x8*)(Ab + aoff + (i) * 1024 + ((s) ? pc1 : pc0)))
#define RDB(j, s) (*(const bf16x8*)(Bb + boff + (j) * 1024 + ((s) ? pc1 : pc0)))

// one phase: ds-read subtile || issue 1 half-tile stage -> bar -> lgkm(0)
// -> setprio(1) -> 16 MFMA -> setprio(0). Caller adds boundary+barrier.
#define DO_PHASE(K_, SS_)                                                     \
  {                                                                           \
    af[0][0] = RDA(2 * (K_), 0);                                              \
    af[0][1] = RDA(2 * (K_), 1);                                              \
    af[1][0] = RDA(2 * (K_) + 1, 0);                                          \
    af[1][1] = RDA(2 * (K_) + 1, 1);                                          \
    if ((K_) == 0) {                                                          \
      bfr[0][0] = RDB(0, 0); bfr[0][1] = RDB(0, 1);                           \
      bfr[1][0] = RDB(1, 0); bfr[1][1] = RDB(1, 1);                           \
      bfr[2][0] = RDB(2, 0); bfr[2][1] = RDB(2, 1);                           \
      bfr[3][0] = RDB(3, 0); bfr[3][1] = RDB(3, 1);                           \
    }                                                                         \
    stage(SS_, aSrc, bSrc, lds, sx);                                          \
    __builtin_amdgcn_s_barrier();                                             \
    asm volatile("s_waitcnt lgkmcnt(0)");                                     \
    __builtin_amdgcn_sched_barrier(0);                                        \
    __builtin_amdgcn_s_setprio(1);                                            \
    _Pragma("unroll") for (int s2 = 0; s2 < 2; ++s2) {                        \
      _Pragma("unroll") for (int j = 0; j < 4; ++j) {                         \
        acc[2 * (K_)][j] = __builtin_amdgcn_mfma_f32_16x16x32_bf16(           \
            af[0][s2], bfr[j][s2], acc[2 * (K_)][j], 0, 0, 0);                \
        acc[2 * (K_) + 1][j] = __builtin_amdgcn_mfma_f32_16x16x32_bf16(       \
            af[1][s2], bfr[j][s2], acc[2 * (K_) + 1][j], 0, 0, 0);            \
      }                                                                       \
    }                                                                         \
    __builtin_amdgcn_s_setprio(0);                                            \
    __builtin_amdgcn_sched_barrier(0);                                        \
  }

#pragma unroll 2
  for (int t = 0; t < NT; ++t) {
    const u16* Ab = lds + ((t & 1) << 1) * LDS_OP;
    const u16* Bb = Ab + LDS_OP;
    int s0 = 4 * t + 6;          // stages A0(t+1),A1(t+1),B0(t+2),B1(t+2)
    DO_PHASE(0, s0)              // i=0,1 ; all B frags
    __builtin_amdgcn_s_barrier();
    DO_PHASE(1, s0 + 1)          // i=2,3
    __builtin_amdgcn_s_barrier();
    DO_PHASE(2, s0 + 2)          // i=4,5 ; B region of cur buf dead -> safe
    __builtin_amdgcn_s_barrier();
    DO_PHASE(3, s0 + 3)          // i=6,7
    // boundary: tile t+1 fully landed; B0/B1(t+2) (4 loads) may stay flying
    if (t < NT - 2) asm volatile("s_waitcnt vmcnt(4)");
    else            asm volatile("s_waitcnt vmcnt(0)");
    __builtin_amdgcn_s_barrier();
  }
#undef DO_PHASE
#undef RDA
#undef RDB

  // Epilogue: n-frag j = gate (i,f,o,c) for hidden cols of sub-block sb.
  int sb = (bcol << 2) + (w & 3);
  int hcol = (sb << 4) + lrow;
  float bi = ib[hcol];
  float bff = fb[hcol];
  float bo = ob[hcol];
  float bc = cb[hcol];

#pragma unroll
  for (int i = 0; i < 8; ++i) {
    int row0 = grow + wr + i * 16 + q * 4;
#pragma unroll
    for (int r = 0; r < 4; ++r) {
      size_t idx = (size_t)(row0 + r) * HID + hcol;
      float gi = sigmoid_fast(acc[i][0][r] + bi);
      float gf = sigmoid_fast(acc[i][1][r] + bff);
      float go = sigmoid_fast(acc[i][2][r] + bo);
      float gc = tanh_fast(acc[i][3][r] + bc);
      float cp = cprev[idx];
      float cv = gf * cp + gi * gc;
      hout[idx] = go * tanh_fast(cv);
      cout[idx] = cv;
    }
  }
}

extern "C" void kernel_launch(void* const* d_in, const int* in_sizes, int n_in,
                              void* d_out, int out_size, void* d_ws, size_t ws_size,
                              hipStream_t stream) {
  const float* x   = (const float*)d_in[0];
  const float* hp  = (const float*)d_in[1];
  const float* cp  = (const float*)d_in[2];
  const float* igx = (const float*)d_in[3];
  const float* igu = (const float*)d_in[4];
  const float* ib  = (const float*)d_in[5];
  const float* fgx = (const float*)d_in[6];
  const float* fgu = (const float*)d_in[7];
  const float* fb  = (const float*)d_in[8];
  const float* ogx = (const float*)d_in[9];
  const float* ogu = (const float*)d_in[10];
  const float* ob  = (const float*)d_in[11];
  const float* cgx = (const float*)d_in[12];
  const float* cgu = (const float*)d_in[13];
  const float* cb  = (const float*)d_in[14];

  u16* bt = (u16*)d_ws;                         // [4096][2048] bf16 = 16 MiB
  u16* xh = bt + (size_t)4096 * 2048;           // [4096][2048] bf16 = 16 MiB
  float* hout = (float*)d_out;
  float* cout = hout + (size_t)BATCH * HID;

  prep_all<<<6144, 256, 0, stream>>>(x, hp, igx, fgx, ogx, cgx,
                                     igu, fgu, ogu, cgu, xh, bt);
  lstm_gemm<<<dim3(16, 16), 512, 0, stream>>>(xh, bt, cp, ib, fb, ob, cb,
                                              hout, cout);
}